// Round 3
// baseline (189.073 us; speedup 1.0000x reference)
//
#include <hip/hip_runtime.h>
#include <math.h>

// FFTConvReservoir: y = tanh(ifft(fft(u)*fft(K)).real + D*u); B=8,H=256,L=8192 fp32.
// Round 11: resubmit of round 10 (bench infra failed twice; no counter evidence of
// a kernel defect — barriers uniform, handoff wave-locality and twiddle pyramids
// re-verified by enumeration).
// Round 10: NT 512->1024. R9 showed LDS (64KB/block, 2 blocks/CU) caps occupancy at
// 16 waves/CU (30% meas, VALUBusy 63%) while VGPR=64 had headroom. 1024-thread
// blocks put 32 waves/CU (8/SIMD, hw max) on the same LDS. 8 elem/thread: pass A =
// 3 stages (spans 4096..1024) -> 8 contiguous 1024-chunks, one per 2-wave group.
// Middle: M1 (512/256/128), M2 (64/32/16), merged M3 (8/4/2 + span-1 via
// __shfl_xor(1) + *kw + span-1 + 2/4/8), M2', M1'. Span-1 butterflies via shuffle
// (partner = adjacent lane, twiddle=1) avoid an extra LDS trip. M2<->M3 handoffs
// verified same-wave (no barrier); barriers = 4. Swizzle SW(e) verified 2-way
// (free) for all five LDS patterns by enumeration. __launch_bounds__(1024,8)
// forces VGPR<=64 (R9 fit 64 with 2x the per-thread state).
// Lessons kept: no b64 LDS (R7), no single-kernel fusion (R4), kw=(FFT(K)+D)/N
// folded in kfft (R6), scalar b32 LDS (R3).

#define LL 8192
#define NT 1024
#define HH 256
#define TWO_PI 6.2831853071795864f
#define CP8  0.92387953251129f    // cos(pi/8)
#define SP8  0.38268343236509f    // sin(pi/8)
#define CP4  0.70710678118654752f // cos(pi/4)
#define SP4  0.70710678118654752f // sin(pi/4)

// Swizzle: XOR e[7] into e[4] (fixes M2's b-aliasing) and e[8:6] into e[3:1]
// (fixes M3's g-aliasing / contiguous t7-aliasing). Strictly high->low bits:
// bijective. All patterns exactly 2-way (free):
//  A/A': e = m<<10 | tid       (lanes vary e[5:0] only)
//  M1:   e = cb | j<<7 | t7    (lanes vary e[5:0] only)
//  M2:   e = cb | b<<7 | j<<4 | r   -> bit4 = j0^b0 separates b-halves
//  M3:   e = cb | g<<4 | j<<1 | par -> bits[3:1] ^= g[4:2], bit4 = g0^g3
__device__ __forceinline__ int SW(int e) {
    return e ^ ((e >> 3) & 0x10) ^ ((e >> 5) & 0x0E);
}
__device__ __forceinline__ float fast_tanh(float x) {
    float e = __expf(2.0f * x);
    return 1.0f - 2.0f / (e + 1.0f);
}

// Twiddle pyramid: level j at offset (1<<j)-1, length 2^j; top level chained cmul,
// lower levels by squaring. Level j entry m = exp(i*2^(JT-j)*(ang0 + m*angE)).
template<int JT>
__device__ __forceinline__ void fill_pyr_cs(float c0, float s0, float Er, float Ei,
                                            float* twr, float* twi) {
    const int off = (1 << JT) - 1;
    twr[off] = c0; twi[off] = s0;
    #pragma unroll
    for (int m = 1; m < (1 << JT); ++m) {
        const float pr = twr[off + m - 1], pi = twi[off + m - 1];
        twr[off + m] = pr * Er - pi * Ei;
        twi[off + m] = pr * Ei + pi * Er;
    }
    #pragma unroll
    for (int j = JT - 1; j >= 0; --j) {
        #pragma unroll
        for (int m = 0; m < (1 << j); ++m) {
            const float a = twr[(2 << j) - 1 + m], b = twi[(2 << j) - 1 + m];
            twr[(1 << j) - 1 + m] = a * a - b * b;
            twi[(1 << j) - 1 + m] = 2.0f * a * b;
        }
    }
}
template<int JT>
__device__ __forceinline__ void fill_pyr(float ang0, float Er, float Ei,
                                         float* twr, float* twi) {
    float s, c;
    __sincosf(ang0, &s, &c);
    fill_pyr_cs<JT>(c, s, Er, Ei, twr, twi);
}

template<int R2>
__device__ __forceinline__ void dif_apply(float* xr, float* xi,
                                          const float* twr, const float* twi) {
    #pragma unroll
    for (int j = R2 - 1; j >= 0; --j) {
        #pragma unroll
        for (int q = 0; q < (1 << (R2 - 1)); ++q) {
            const int mm = q & ((1 << j) - 1);
            const int m0 = ((q >> j) << (j + 1)) | mm;
            const int m1 = m0 + (1 << j);
            const float wr = twr[(1 << j) - 1 + mm], wi = twi[(1 << j) - 1 + mm];
            const float ar = xr[m0], ai = xi[m0], br = xr[m1], bi = xi[m1];
            xr[m0] = ar + br; xi[m0] = ai + bi;
            const float dr = ar - br, di = ai - bi;
            xr[m1] = dr * wr - di * wi;
            xi[m1] = dr * wi + di * wr;
        }
    }
}
template<int R2>
__device__ __forceinline__ void dit_apply(float* xr, float* xi,
                                          const float* twr, const float* twi) {
    #pragma unroll
    for (int j = 0; j < R2; ++j) {
        #pragma unroll
        for (int q = 0; q < (1 << (R2 - 1)); ++q) {
            const int mm = q & ((1 << j) - 1);
            const int m0 = ((q >> j) << (j + 1)) | mm;
            const int m1 = m0 + (1 << j);
            const float wr = twr[(1 << j) - 1 + mm], wi = twi[(1 << j) - 1 + mm];
            const float br = xr[m1] * wr - xi[m1] * wi;
            const float bi = xr[m1] * wi + xi[m1] * wr;
            const float ar = xr[m0], ai = xi[m0];
            xr[m0] = ar + br; xi[m0] = ai + bi;
            xr[m1] = ar - br; xi[m1] = ai - bi;
        }
    }
}
// dit with conjugated twiddles (reuse the forward pyramid; negation is a free
// VOP3 input modifier).
template<int R2>
__device__ __forceinline__ void dit_apply_c(float* xr, float* xi,
                                            const float* twr, const float* twi) {
    #pragma unroll
    for (int j = 0; j < R2; ++j) {
        #pragma unroll
        for (int q = 0; q < (1 << (R2 - 1)); ++q) {
            const int mm = q & ((1 << j) - 1);
            const int m0 = ((q >> j) << (j + 1)) | mm;
            const int m1 = m0 + (1 << j);
            const float wr = twr[(1 << j) - 1 + mm], wi = -twi[(1 << j) - 1 + mm];
            const float br = xr[m1] * wr - xi[m1] * wi;
            const float bi = xr[m1] * wi + xi[m1] * wr;
            const float ar = xr[m0], ai = xi[m0];
            xr[m0] = ar + br; xi[m0] = ai + bi;
            xr[m1] = ar - br; xi[m1] = ai - bi;
        }
    }
}

// Span-1 butterfly across adjacent lanes (twiddle = 1). Even lane (par=0) holds
// position n, odd (par=1) holds n+1: out_n = a+b, out_{n+1} = a-b. Same formula
// fwd (DIF last stage) and inv (DIT first stage). s = par ? -1 : +1.
__device__ __forceinline__ void bfly1_shfl(float* yr, float* yi, float s) {
    #pragma unroll
    for (int j = 0; j < 8; ++j) {
        const float vr = __shfl_xor(yr[j], 1);
        const float vi = __shfl_xor(yi[j], 1);
        yr[j] = fmaf(yr[j], s, vr);
        yi[j] = fmaf(yi[j], s, vi);
    }
}

// Fwd pass A (spans 4096,2048,1024): 8 elements per thread at stride 1024.
// After this, chunk c = contiguous [1024c, 1024c+1024), local offset = tid&1023.
__device__ __forceinline__ void fwd_A(float* xr, float* xi, int tid,
                                      float* re, float* im) {
    float twr[7], twi[7];
    fill_pyr<2>(-(TWO_PI / 8192.0f) * (float)tid, CP4, -SP4, twr, twi);
    dif_apply<3>(xr, xi, twr, twi);
    #pragma unroll
    for (int m = 0; m < 8; ++m) {
        const int p = SW(tid + (m << 10));
        re[p] = xr[m]; im[p] = xi[m];
    }
}

// M1: spans 512/256/128 within a 1024-chunk. Elements t7 + 128j.
template<bool INV>
__device__ __forceinline__ void mid_M1(float* re, float* im, int t7, int cb) {
    float twr[7], twi[7];
    const float sgn = INV ? 1.0f : -1.0f;
    fill_pyr<2>(sgn * (TWO_PI / 1024.0f) * (float)t7, CP4, sgn * SP4, twr, twi);
    const int base = cb + t7;
    float ar[8], ai[8];
    #pragma unroll
    for (int j = 0; j < 8; ++j) {
        const int p = SW(base + (j << 7));
        ar[j] = re[p]; ai[j] = im[p];
    }
    if (INV) dit_apply<3>(ar, ai, twr, twi);
    else     dif_apply<3>(ar, ai, twr, twi);
    #pragma unroll
    for (int j = 0; j < 8; ++j) {
        const int p = SW(base + (j << 7));
        re[p] = ar[j]; im[p] = ai[j];
    }
}

// M2: spans 64/32/16 within each 128-block. t7 -> (b = t7>>4, r = t7&15),
// elements b*128 + r + 16j.
template<bool INV>
__device__ __forceinline__ void mid_M2(float* re, float* im, int t7, int cb) {
    float twr[7], twi[7];
    const float sgn = INV ? 1.0f : -1.0f;
    const int r_ = t7 & 15;
    fill_pyr<2>(sgn * (TWO_PI / 128.0f) * (float)r_, CP4, sgn * SP4, twr, twi);
    const int base = cb + ((t7 >> 4) << 7) + r_;
    float ar[8], ai[8];
    #pragma unroll
    for (int j = 0; j < 8; ++j) {
        const int p = SW(base + (j << 4));
        ar[j] = re[p]; ai[j] = im[p];
    }
    if (INV) dit_apply<3>(ar, ai, twr, twi);
    else     dif_apply<3>(ar, ai, twr, twi);
    #pragma unroll
    for (int j = 0; j < 8; ++j) {
        const int p = SW(base + (j << 4));
        re[p] = ar[j]; im[p] = ai[j];
    }
}

__global__ __launch_bounds__(NT, 8) void kfft_kernel(const float* __restrict__ K,
                                                     const float* __restrict__ D,
                                                     float2* __restrict__ Kf) {
    __shared__ float re[LL];
    __shared__ float im[LL];
    const int h = blockIdx.x;
    const int tid = threadIdx.x;
    const float* Kr = K + (size_t)h * LL;
    float xr[8], xi[8];
    #pragma unroll
    for (int m = 0; m < 8; ++m) {
        xr[m] = Kr[tid + (m << 10)];
        xi[m] = 0.0f;
    }
    fwd_A(xr, xi, tid, re, im);
    __syncthreads();

    const int t7 = tid & 127;
    const int cb = (tid >> 7) << 10;
    mid_M1<false>(re, im, t7, cb);
    __syncthreads();
    mid_M2<false>(re, im, t7, cb);
    // wave-local handoff M2 -> M3 (no barrier)

    // M3 fwd (spans 8,4,2 on stride-2 elems) + span-1 via shfl + fold
    // kw = (X + D[h])/N, store in conv's register order (contiguous 64B/thread).
    {
        const int g_ = t7 >> 1, par = t7 & 1;
        const float dh = D[h];
        const float invN = 1.0f / (float)LL;
        float twr[7], twi[7];
        fill_pyr_cs<2>(par ? CP8 : 1.0f, par ? -SP8 : 0.0f, CP4, -SP4, twr, twi);
        const int base = cb + (g_ << 4) + par;
        const float s = par ? -1.0f : 1.0f;
        float yr[8], yi[8];
        #pragma unroll
        for (int j = 0; j < 8; ++j) {
            const int p = SW(base + (j << 1));
            yr[j] = re[p]; yi[j] = im[p];
        }
        dif_apply<3>(yr, yi, twr, twi);
        bfly1_shfl(yr, yi, s);
        float4* o4 = (float4*)(Kf + (size_t)h * LL + cb + (t7 << 3));
        #pragma unroll
        for (int jj = 0; jj < 4; ++jj) {
            float4 v;
            v.x = (yr[2 * jj]     + dh) * invN; v.y = yi[2 * jj]     * invN;
            v.z = (yr[2 * jj + 1] + dh) * invN; v.w = yi[2 * jj + 1] * invN;
            o4[jj] = v;
        }
    }
}

__global__ __launch_bounds__(NT, 8) void conv_kernel(const float* __restrict__ u,
                                                     const float2* __restrict__ Kf,
                                                     float* __restrict__ out) {
    __shared__ float re[LL];
    __shared__ float im[LL];
    const int tid = threadIdx.x;
    const int h = blockIdx.x & (HH - 1);
    const int pr_ = blockIdx.x >> 8;        // batch pair 0..3
    const size_t off0 = ((size_t)(pr_ * 2) * HH + h) * LL;
    const size_t off1 = off0 + (size_t)HH * LL;
    const float* u0 = u + off0;
    const float* u1 = u + off1;

    float xr[8], xi[8];
    #pragma unroll
    for (int m = 0; m < 8; ++m) {
        xr[m] = u0[tid + (m << 10)];
        xi[m] = u1[tid + (m << 10)];
    }
    fwd_A(xr, xi, tid, re, im);       // z = u0 + i*u1
    __syncthreads();

    const int t7 = tid & 127;
    const int cb = (tid >> 7) << 10;

    // kw prefetch (4x dwordx4, contiguous 64B/thread), consumed in M3 after
    // M1+M2 (~2 LDS trips of latency cover).
    float kwr[8], kwi[8];
    {
        const float4* kp = (const float4*)(Kf + (size_t)h * LL + cb + (t7 << 3));
        #pragma unroll
        for (int jj = 0; jj < 4; ++jj) {
            const float4 v = kp[jj];
            kwr[2 * jj]     = v.x; kwi[2 * jj]     = v.y;
            kwr[2 * jj + 1] = v.z; kwi[2 * jj + 1] = v.w;
        }
    }

    mid_M1<false>(re, im, t7, cb);
    __syncthreads();
    mid_M2<false>(re, im, t7, cb);
    // wave-local handoff M2 -> M3 (no barrier)

    // Merged M3: spans 8,4,2 fwd; span-1 fwd (shfl); *kw; span-1 inv (shfl);
    // spans 2,4,8 inv (conjugate pyramid reused).
    {
        const int g_ = t7 >> 1, par = t7 & 1;
        float twr[7], twi[7];
        fill_pyr_cs<2>(par ? CP8 : 1.0f, par ? -SP8 : 0.0f, CP4, -SP4, twr, twi);
        const int base = cb + (g_ << 4) + par;
        const float s = par ? -1.0f : 1.0f;
        float yr[8], yi[8];
        #pragma unroll
        for (int j = 0; j < 8; ++j) {
            const int p = SW(base + (j << 1));
            yr[j] = re[p]; yi[j] = im[p];
        }
        dif_apply<3>(yr, yi, twr, twi);
        bfly1_shfl(yr, yi, s);
        #pragma unroll
        for (int j = 0; j < 8; ++j) {
            const float a = yr[j], bb = yi[j];
            yr[j] = a * kwr[j] - bb * kwi[j];
            yi[j] = a * kwi[j] + bb * kwr[j];
        }
        bfly1_shfl(yr, yi, s);
        dit_apply_c<3>(yr, yi, twr, twi);
        #pragma unroll
        for (int j = 0; j < 8; ++j) {
            const int p = SW(base + (j << 1));
            re[p] = yr[j]; im[p] = yi[j];
        }
    }
    // wave-local handoff M3 -> M2' (no barrier)

    mid_M2<true>(re, im, t7, cb);
    __syncthreads();
    mid_M1<true>(re, im, t7, cb);
    __syncthreads();

    // Inv pass A' (spans 1024,2048,4096) + epilogue (skip/norm folded into kw).
    {
        float twr[7], twi[7];
        #pragma unroll
        for (int m = 0; m < 8; ++m) {
            const int p = SW(tid + (m << 10));
            xr[m] = re[p]; xi[m] = im[p];
        }
        fill_pyr<2>((TWO_PI / 8192.0f) * (float)tid, CP4, SP4, twr, twi);
        dit_apply<3>(xr, xi, twr, twi);
    }
    float* o0 = out + off0;
    float* o1 = out + off1;
    #pragma unroll
    for (int m = 0; m < 8; ++m) {
        const int n = tid + (m << 10);
        o0[n] = fast_tanh(xr[m]);
        o1[n] = fast_tanh(xi[m]);
    }
}

extern "C" void kernel_launch(void* const* d_in, const int* in_sizes, int n_in,
                              void* d_out, int out_size, void* d_ws, size_t ws_size,
                              hipStream_t stream) {
    const float* u = (const float*)d_in[0];   // (8, 256, 8192)
    const float* K = (const float*)d_in[1];   // (256, 8192)
    const float* D = (const float*)d_in[2];   // (256,)
    float* out = (float*)d_out;               // (8, 256, 8192)
    float2* Kf = (float2*)d_ws;               // 256 * 8192 float2 = 16 MB

    kfft_kernel<<<dim3(HH), dim3(NT), 0, stream>>>(K, D, Kf);
    conv_kernel<<<dim3(4 * HH), dim3(NT), 0, stream>>>(u, Kf, out);
}

// Round 4
// 162.630 us; speedup vs baseline: 1.1626x; 1.1626x over previous
//
#include <hip/hip_runtime.h>
#include <math.h>

// FFTConvReservoir: y = tanh(ifft(fft(u)*fft(K)).real + D*u); B=8,H=256,L=8192 fp32.
// Round 12: fix R11's spill. Counters showed VGPR=32 + WRITE_SIZE 3x (scratch):
// __launch_bounds__ 2nd arg is MIN BLOCKS/CU (CUDA semantics) on hipcc — evidence:
// (512,4) -> VGPR 64 = 512/(4*8/4 waves per SIMD); (1024,8) -> VGPR 32 (asked for
// 8-block residency = 32 waves/SIMD, impossible). (1024,2) = 2 blocks x 16 waves =
// 32 waves/CU = 8/SIMD -> VGPR cap 64, exactly the design point (LDS fits 2 blocks).
// Round 10 structure kept: NT=1024, 8 elem/thread, pass A = 3 stages (spans
// 4096..1024) -> 8 contiguous 1024-chunks, one per 2-wave group. Middle: M1
// (512/256/128), M2 (64/32/16), merged M3 (8/4/2 + span-1 via __shfl_xor(1) + *kw
// + span-1 + 2/4/8), M2', M1'. M2<->M3 handoffs same-wave (no barrier); barriers=4.
// Swizzle SW(e) 2-way (free) for all five LDS patterns (verified by enumeration).
// Lessons kept: no b64 LDS (R7), no single-kernel fusion (R4), kw=(FFT(K)+D)/N
// folded in kfft (R6), scalar b32 LDS (R3).

#define LL 8192
#define NT 1024
#define HH 256
#define TWO_PI 6.2831853071795864f
#define CP8  0.92387953251129f    // cos(pi/8)
#define SP8  0.38268343236509f    // sin(pi/8)
#define CP4  0.70710678118654752f // cos(pi/4)
#define SP4  0.70710678118654752f // sin(pi/4)

// Swizzle: XOR e[7] into e[4] (fixes M2's b-aliasing) and e[8:6] into e[3:1]
// (fixes M3's g-aliasing / contiguous t7-aliasing). Strictly high->low bits:
// bijective. All patterns exactly 2-way (free):
//  A/A': e = m<<10 | tid       (lanes vary e[5:0] only)
//  M1:   e = cb | j<<7 | t7    (lanes vary e[5:0] only)
//  M2:   e = cb | b<<7 | j<<4 | r   -> bit4 = j0^b0 separates b-halves
//  M3:   e = cb | g<<4 | j<<1 | par -> bits[3:1] ^= g[4:2], bit4 = g0^g3
__device__ __forceinline__ int SW(int e) {
    return e ^ ((e >> 3) & 0x10) ^ ((e >> 5) & 0x0E);
}
__device__ __forceinline__ float fast_tanh(float x) {
    float e = __expf(2.0f * x);
    return 1.0f - 2.0f / (e + 1.0f);
}

// Twiddle pyramid: level j at offset (1<<j)-1, length 2^j; top level chained cmul,
// lower levels by squaring. Level j entry m = exp(i*2^(JT-j)*(ang0 + m*angE)).
template<int JT>
__device__ __forceinline__ void fill_pyr_cs(float c0, float s0, float Er, float Ei,
                                            float* twr, float* twi) {
    const int off = (1 << JT) - 1;
    twr[off] = c0; twi[off] = s0;
    #pragma unroll
    for (int m = 1; m < (1 << JT); ++m) {
        const float pr = twr[off + m - 1], pi = twi[off + m - 1];
        twr[off + m] = pr * Er - pi * Ei;
        twi[off + m] = pr * Ei + pi * Er;
    }
    #pragma unroll
    for (int j = JT - 1; j >= 0; --j) {
        #pragma unroll
        for (int m = 0; m < (1 << j); ++m) {
            const float a = twr[(2 << j) - 1 + m], b = twi[(2 << j) - 1 + m];
            twr[(1 << j) - 1 + m] = a * a - b * b;
            twi[(1 << j) - 1 + m] = 2.0f * a * b;
        }
    }
}
template<int JT>
__device__ __forceinline__ void fill_pyr(float ang0, float Er, float Ei,
                                         float* twr, float* twi) {
    float s, c;
    __sincosf(ang0, &s, &c);
    fill_pyr_cs<JT>(c, s, Er, Ei, twr, twi);
}

template<int R2>
__device__ __forceinline__ void dif_apply(float* xr, float* xi,
                                          const float* twr, const float* twi) {
    #pragma unroll
    for (int j = R2 - 1; j >= 0; --j) {
        #pragma unroll
        for (int q = 0; q < (1 << (R2 - 1)); ++q) {
            const int mm = q & ((1 << j) - 1);
            const int m0 = ((q >> j) << (j + 1)) | mm;
            const int m1 = m0 + (1 << j);
            const float wr = twr[(1 << j) - 1 + mm], wi = twi[(1 << j) - 1 + mm];
            const float ar = xr[m0], ai = xi[m0], br = xr[m1], bi = xi[m1];
            xr[m0] = ar + br; xi[m0] = ai + bi;
            const float dr = ar - br, di = ai - bi;
            xr[m1] = dr * wr - di * wi;
            xi[m1] = dr * wi + di * wr;
        }
    }
}
template<int R2>
__device__ __forceinline__ void dit_apply(float* xr, float* xi,
                                          const float* twr, const float* twi) {
    #pragma unroll
    for (int j = 0; j < R2; ++j) {
        #pragma unroll
        for (int q = 0; q < (1 << (R2 - 1)); ++q) {
            const int mm = q & ((1 << j) - 1);
            const int m0 = ((q >> j) << (j + 1)) | mm;
            const int m1 = m0 + (1 << j);
            const float wr = twr[(1 << j) - 1 + mm], wi = twi[(1 << j) - 1 + mm];
            const float br = xr[m1] * wr - xi[m1] * wi;
            const float bi = xr[m1] * wi + xi[m1] * wr;
            const float ar = xr[m0], ai = xi[m0];
            xr[m0] = ar + br; xi[m0] = ai + bi;
            xr[m1] = ar - br; xi[m1] = ai - bi;
        }
    }
}
// dit with conjugated twiddles (reuse the forward pyramid; negation is a free
// VOP3 input modifier).
template<int R2>
__device__ __forceinline__ void dit_apply_c(float* xr, float* xi,
                                            const float* twr, const float* twi) {
    #pragma unroll
    for (int j = 0; j < R2; ++j) {
        #pragma unroll
        for (int q = 0; q < (1 << (R2 - 1)); ++q) {
            const int mm = q & ((1 << j) - 1);
            const int m0 = ((q >> j) << (j + 1)) | mm;
            const int m1 = m0 + (1 << j);
            const float wr = twr[(1 << j) - 1 + mm], wi = -twi[(1 << j) - 1 + mm];
            const float br = xr[m1] * wr - xi[m1] * wi;
            const float bi = xr[m1] * wi + xi[m1] * wr;
            const float ar = xr[m0], ai = xi[m0];
            xr[m0] = ar + br; xi[m0] = ai + bi;
            xr[m1] = ar - br; xi[m1] = ai - bi;
        }
    }
}

// Span-1 butterfly across adjacent lanes (twiddle = 1). Even lane (par=0) holds
// position n, odd (par=1) holds n+1: out_n = a+b, out_{n+1} = a-b. Same formula
// fwd (DIF last stage) and inv (DIT first stage). s = par ? -1 : +1.
__device__ __forceinline__ void bfly1_shfl(float* yr, float* yi, float s) {
    #pragma unroll
    for (int j = 0; j < 8; ++j) {
        const float vr = __shfl_xor(yr[j], 1);
        const float vi = __shfl_xor(yi[j], 1);
        yr[j] = fmaf(yr[j], s, vr);
        yi[j] = fmaf(yi[j], s, vi);
    }
}

// Fwd pass A (spans 4096,2048,1024): 8 elements per thread at stride 1024.
// After this, chunk c = contiguous [1024c, 1024c+1024), local offset = tid&1023.
__device__ __forceinline__ void fwd_A(float* xr, float* xi, int tid,
                                      float* re, float* im) {
    float twr[7], twi[7];
    fill_pyr<2>(-(TWO_PI / 8192.0f) * (float)tid, CP4, -SP4, twr, twi);
    dif_apply<3>(xr, xi, twr, twi);
    #pragma unroll
    for (int m = 0; m < 8; ++m) {
        const int p = SW(tid + (m << 10));
        re[p] = xr[m]; im[p] = xi[m];
    }
}

// M1: spans 512/256/128 within a 1024-chunk. Elements t7 + 128j.
template<bool INV>
__device__ __forceinline__ void mid_M1(float* re, float* im, int t7, int cb) {
    float twr[7], twi[7];
    const float sgn = INV ? 1.0f : -1.0f;
    fill_pyr<2>(sgn * (TWO_PI / 1024.0f) * (float)t7, CP4, sgn * SP4, twr, twi);
    const int base = cb + t7;
    float ar[8], ai[8];
    #pragma unroll
    for (int j = 0; j < 8; ++j) {
        const int p = SW(base + (j << 7));
        ar[j] = re[p]; ai[j] = im[p];
    }
    if (INV) dit_apply<3>(ar, ai, twr, twi);
    else     dif_apply<3>(ar, ai, twr, twi);
    #pragma unroll
    for (int j = 0; j < 8; ++j) {
        const int p = SW(base + (j << 7));
        re[p] = ar[j]; im[p] = ai[j];
    }
}

// M2: spans 64/32/16 within each 128-block. t7 -> (b = t7>>4, r = t7&15),
// elements b*128 + r + 16j.
template<bool INV>
__device__ __forceinline__ void mid_M2(float* re, float* im, int t7, int cb) {
    float twr[7], twi[7];
    const float sgn = INV ? 1.0f : -1.0f;
    const int r_ = t7 & 15;
    fill_pyr<2>(sgn * (TWO_PI / 128.0f) * (float)r_, CP4, sgn * SP4, twr, twi);
    const int base = cb + ((t7 >> 4) << 7) + r_;
    float ar[8], ai[8];
    #pragma unroll
    for (int j = 0; j < 8; ++j) {
        const int p = SW(base + (j << 4));
        ar[j] = re[p]; ai[j] = im[p];
    }
    if (INV) dit_apply<3>(ar, ai, twr, twi);
    else     dif_apply<3>(ar, ai, twr, twi);
    #pragma unroll
    for (int j = 0; j < 8; ++j) {
        const int p = SW(base + (j << 4));
        re[p] = ar[j]; im[p] = ai[j];
    }
}

__global__ __launch_bounds__(NT, 2) void kfft_kernel(const float* __restrict__ K,
                                                     const float* __restrict__ D,
                                                     float2* __restrict__ Kf) {
    __shared__ float re[LL];
    __shared__ float im[LL];
    const int h = blockIdx.x;
    const int tid = threadIdx.x;
    const float* Kr = K + (size_t)h * LL;
    float xr[8], xi[8];
    #pragma unroll
    for (int m = 0; m < 8; ++m) {
        xr[m] = Kr[tid + (m << 10)];
        xi[m] = 0.0f;
    }
    fwd_A(xr, xi, tid, re, im);
    __syncthreads();

    const int t7 = tid & 127;
    const int cb = (tid >> 7) << 10;
    mid_M1<false>(re, im, t7, cb);
    __syncthreads();
    mid_M2<false>(re, im, t7, cb);
    // wave-local handoff M2 -> M3 (no barrier)

    // M3 fwd (spans 8,4,2 on stride-2 elems) + span-1 via shfl + fold
    // kw = (X + D[h])/N, store in conv's register order (contiguous 64B/thread).
    {
        const int g_ = t7 >> 1, par = t7 & 1;
        const float dh = D[h];
        const float invN = 1.0f / (float)LL;
        float twr[7], twi[7];
        fill_pyr_cs<2>(par ? CP8 : 1.0f, par ? -SP8 : 0.0f, CP4, -SP4, twr, twi);
        const int base = cb + (g_ << 4) + par;
        const float s = par ? -1.0f : 1.0f;
        float yr[8], yi[8];
        #pragma unroll
        for (int j = 0; j < 8; ++j) {
            const int p = SW(base + (j << 1));
            yr[j] = re[p]; yi[j] = im[p];
        }
        dif_apply<3>(yr, yi, twr, twi);
        bfly1_shfl(yr, yi, s);
        float4* o4 = (float4*)(Kf + (size_t)h * LL + cb + (t7 << 3));
        #pragma unroll
        for (int jj = 0; jj < 4; ++jj) {
            float4 v;
            v.x = (yr[2 * jj]     + dh) * invN; v.y = yi[2 * jj]     * invN;
            v.z = (yr[2 * jj + 1] + dh) * invN; v.w = yi[2 * jj + 1] * invN;
            o4[jj] = v;
        }
    }
}

__global__ __launch_bounds__(NT, 2) void conv_kernel(const float* __restrict__ u,
                                                     const float2* __restrict__ Kf,
                                                     float* __restrict__ out) {
    __shared__ float re[LL];
    __shared__ float im[LL];
    const int tid = threadIdx.x;
    const int h = blockIdx.x & (HH - 1);
    const int pr_ = blockIdx.x >> 8;        // batch pair 0..3
    const size_t off0 = ((size_t)(pr_ * 2) * HH + h) * LL;
    const size_t off1 = off0 + (size_t)HH * LL;
    const float* u0 = u + off0;
    const float* u1 = u + off1;

    float xr[8], xi[8];
    #pragma unroll
    for (int m = 0; m < 8; ++m) {
        xr[m] = u0[tid + (m << 10)];
        xi[m] = u1[tid + (m << 10)];
    }
    fwd_A(xr, xi, tid, re, im);       // z = u0 + i*u1
    __syncthreads();

    const int t7 = tid & 127;
    const int cb = (tid >> 7) << 10;

    // kw prefetch (4x dwordx4, contiguous 64B/thread), consumed in M3 after
    // M1+M2 (~2 LDS trips of latency cover).
    float kwr[8], kwi[8];
    {
        const float4* kp = (const float4*)(Kf + (size_t)h * LL + cb + (t7 << 3));
        #pragma unroll
        for (int jj = 0; jj < 4; ++jj) {
            const float4 v = kp[jj];
            kwr[2 * jj]     = v.x; kwi[2 * jj]     = v.y;
            kwr[2 * jj + 1] = v.z; kwi[2 * jj + 1] = v.w;
        }
    }

    mid_M1<false>(re, im, t7, cb);
    __syncthreads();
    mid_M2<false>(re, im, t7, cb);
    // wave-local handoff M2 -> M3 (no barrier)

    // Merged M3: spans 8,4,2 fwd; span-1 fwd (shfl); *kw; span-1 inv (shfl);
    // spans 2,4,8 inv (conjugate pyramid reused).
    {
        const int g_ = t7 >> 1, par = t7 & 1;
        float twr[7], twi[7];
        fill_pyr_cs<2>(par ? CP8 : 1.0f, par ? -SP8 : 0.0f, CP4, -SP4, twr, twi);
        const int base = cb + (g_ << 4) + par;
        const float s = par ? -1.0f : 1.0f;
        float yr[8], yi[8];
        #pragma unroll
        for (int j = 0; j < 8; ++j) {
            const int p = SW(base + (j << 1));
            yr[j] = re[p]; yi[j] = im[p];
        }
        dif_apply<3>(yr, yi, twr, twi);
        bfly1_shfl(yr, yi, s);
        #pragma unroll
        for (int j = 0; j < 8; ++j) {
            const float a = yr[j], bb = yi[j];
            yr[j] = a * kwr[j] - bb * kwi[j];
            yi[j] = a * kwi[j] + bb * kwr[j];
        }
        bfly1_shfl(yr, yi, s);
        dit_apply_c<3>(yr, yi, twr, twi);
        #pragma unroll
        for (int j = 0; j < 8; ++j) {
            const int p = SW(base + (j << 1));
            re[p] = yr[j]; im[p] = yi[j];
        }
    }
    // wave-local handoff M3 -> M2' (no barrier)

    mid_M2<true>(re, im, t7, cb);
    __syncthreads();
    mid_M1<true>(re, im, t7, cb);
    __syncthreads();

    // Inv pass A' (spans 1024,2048,4096) + epilogue (skip/norm folded into kw).
    {
        float twr[7], twi[7];
        #pragma unroll
        for (int m = 0; m < 8; ++m) {
            const int p = SW(tid + (m << 10));
            xr[m] = re[p]; xi[m] = im[p];
        }
        fill_pyr<2>((TWO_PI / 8192.0f) * (float)tid, CP4, SP4, twr, twi);
        dit_apply<3>(xr, xi, twr, twi);
    }
    float* o0 = out + off0;
    float* o1 = out + off1;
    #pragma unroll
    for (int m = 0; m < 8; ++m) {
        const int n = tid + (m << 10);
        o0[n] = fast_tanh(xr[m]);
        o1[n] = fast_tanh(xi[m]);
    }
}

extern "C" void kernel_launch(void* const* d_in, const int* in_sizes, int n_in,
                              void* d_out, int out_size, void* d_ws, size_t ws_size,
                              hipStream_t stream) {
    const float* u = (const float*)d_in[0];   // (8, 256, 8192)
    const float* K = (const float*)d_in[1];   // (256, 8192)
    const float* D = (const float*)d_in[2];   // (256,)
    float* out = (float*)d_out;               // (8, 256, 8192)
    float2* Kf = (float2*)d_ws;               // 256 * 8192 float2 = 16 MB

    kfft_kernel<<<dim3(HH), dim3(NT), 0, stream>>>(K, D, Kf);
    conv_kernel<<<dim3(4 * HH), dim3(NT), 0, stream>>>(u, Kf, out);
}

// Round 5
// 154.417 us; speedup vs baseline: 1.2244x; 1.0532x over previous
//
#include <hip/hip_runtime.h>
#include <math.h>

// FFTConvReservoir: y = tanh(ifft(fft(u)*fft(K)).real + D*u); B=8,H=256,L=8192 fp32.
// Round 13: (a) conv reverted verbatim to the verified-best R9 kernel (NT=512,
// wave-private middle, 2 barriers, 53.2 us measured). NT=1024 variants are a dead
// end: R12 showed occupancy up (37%) but VALUBusy down (56%) and conv 65.6 us —
// the extra mid barriers + shuffle stages cost more than occupancy bought.
// (b) kfft restructured for parallelism: it was ~60-90 us of the wall (non-conv
// time ~97 us across rounds) at 1 block/CU, 25% max occupancy, one 13-stage
// dependency chain per block. R11's accidental datum: spilled-but-68%-occupancy
// kfft made non-conv drop to 77 us -> kfft is latency-starved, not compute-bound.
// New: kfft1 (elementwise DIF spans 4096+2048: 4 reals -> 4 complex per thread,
// fully streaming, 2048 blocks) + kfft2 (independent 2048-pt FFT per block,
// grid 1024, NT=256, 16KB LDS, 1 barrier, in-place on Kf, spans 2/1 via shfl_xor,
// D/invN folded). All kfft2 LDS patterns exactly 2-way under SW2; M1->M2 handoff
// same-wave (writer & reader tids both in wave blk>>4) -> no barrier.
// Lessons kept: no b64 LDS (R7), no single-kernel fusion (R4), kw=(FFT(K)+D)/N
// folded into Kf (R6), scalar b32 LDS (R3), launch_bounds 2nd arg = min
// blocks/CU (R11/R12: (512,4) -> VGPR 64, (1024,8) -> VGPR 32 + spill).

#define LL 8192
#define NT 512
#define HH 256
#define TWO_PI 6.2831853071795864f
#define CP8  0.92387953251129f    // cos(pi/8)
#define SP8  0.38268343236509f    // sin(pi/8)
#define CP4  0.70710678118654752f // cos(pi/4)
#define SP4  0.70710678118654752f // sin(pi/4)

// conv swizzle (NT=512 layout): XOR bits [8:6] into [2:0] and [7:6] into [4:3].
// Verified 2-way (free) for A/A' (stride-512 scatter), M1 (stride-64), M2
// (8-block), M3 (contig-8) patterns.
__device__ __forceinline__ int SW(int e) {
    return e ^ ((e >> 3) & 0x18) ^ ((e >> 5) & 0x0E);
}
// kfft2 swizzle (2048-elem LDS): XOR e[7:5] into bank bits [4:2]. Verified 2-way
// for reg-pass write (tid+256m), M1 (sub*256+t+32j, e[7:5]=j uniform), M2 read
// (blk*32+r+4j, bank = (j^blk&7)<<2 | r -> 32 distinct per instr).
__device__ __forceinline__ int SW2(int e) {
    return e ^ (((e >> 5) & 7) << 2);
}
__device__ __forceinline__ float fast_tanh(float x) {
    float e = __expf(2.0f * x);
    return 1.0f - 2.0f / (e + 1.0f);
}

// Twiddle pyramid: level j at offset (1<<j)-1, length 2^j; top level chained cmul,
// lower levels by squaring.
template<int JT>
__device__ __forceinline__ void fill_pyr_cs(float c0, float s0, float Er, float Ei,
                                            float* twr, float* twi) {
    const int off = (1 << JT) - 1;
    twr[off] = c0; twi[off] = s0;
    #pragma unroll
    for (int m = 1; m < (1 << JT); ++m) {
        const float pr = twr[off + m - 1], pi = twi[off + m - 1];
        twr[off + m] = pr * Er - pi * Ei;
        twi[off + m] = pr * Ei + pi * Er;
    }
    #pragma unroll
    for (int j = JT - 1; j >= 0; --j) {
        #pragma unroll
        for (int m = 0; m < (1 << j); ++m) {
            const float a = twr[(2 << j) - 1 + m], b = twi[(2 << j) - 1 + m];
            twr[(1 << j) - 1 + m] = a * a - b * b;
            twi[(1 << j) - 1 + m] = 2.0f * a * b;
        }
    }
}
template<int JT>
__device__ __forceinline__ void fill_pyr(float ang0, float Er, float Ei,
                                         float* twr, float* twi) {
    float s, c;
    __sincosf(ang0, &s, &c);
    fill_pyr_cs<JT>(c, s, Er, Ei, twr, twi);
}

template<int R2>
__device__ __forceinline__ void dif_apply(float* xr, float* xi,
                                          const float* twr, const float* twi) {
    #pragma unroll
    for (int j = R2 - 1; j >= 0; --j) {
        #pragma unroll
        for (int q = 0; q < (1 << (R2 - 1)); ++q) {
            const int mm = q & ((1 << j) - 1);
            const int m0 = ((q >> j) << (j + 1)) | mm;
            const int m1 = m0 + (1 << j);
            const float wr = twr[(1 << j) - 1 + mm], wi = twi[(1 << j) - 1 + mm];
            const float ar = xr[m0], ai = xi[m0], br = xr[m1], bi = xi[m1];
            xr[m0] = ar + br; xi[m0] = ai + bi;
            const float dr = ar - br, di = ai - bi;
            xr[m1] = dr * wr - di * wi;
            xi[m1] = dr * wi + di * wr;
        }
    }
}
template<int R2>
__device__ __forceinline__ void dit_apply(float* xr, float* xi,
                                          const float* twr, const float* twi) {
    #pragma unroll
    for (int j = 0; j < R2; ++j) {
        #pragma unroll
        for (int q = 0; q < (1 << (R2 - 1)); ++q) {
            const int mm = q & ((1 << j) - 1);
            const int m0 = ((q >> j) << (j + 1)) | mm;
            const int m1 = m0 + (1 << j);
            const float wr = twr[(1 << j) - 1 + mm], wi = twi[(1 << j) - 1 + mm];
            const float br = xr[m1] * wr - xi[m1] * wi;
            const float bi = xr[m1] * wi + xi[m1] * wr;
            const float ar = xr[m0], ai = xi[m0];
            xr[m0] = ar + br; xi[m0] = ai + bi;
            xr[m1] = ar - br; xi[m1] = ai - bi;
        }
    }
}

// ---------------- conv (verbatim R9 structure, NT=512) ----------------

// Fwd pass A (spans 4096..512): 16 elements per thread at stride 512.
__device__ __forceinline__ void fwd_A(float* xr, float* xi, int tid,
                                      float* re, float* im) {
    float twr[15], twi[15];
    fill_pyr<3>(-(TWO_PI / 8192.0f) * (float)tid, CP8, -SP8, twr, twi);
    dif_apply<4>(xr, xi, twr, twi);
    #pragma unroll
    for (int m = 0; m < 16; ++m) {
        const int p = SW(tid + (m << 9));
        re[p] = xr[m]; im[p] = xi[m];
    }
}

// M1: spans 256/128/64 within a 512-chunk. Elements lane + 64j.
template<bool INV>
__device__ __forceinline__ void mid_M1(float* re, float* im, int lane, int wv) {
    float twr[7], twi[7];
    const float sgn = INV ? 1.0f : -1.0f;
    fill_pyr<2>(sgn * (TWO_PI / 512.0f) * (float)lane, CP4, sgn * SP4, twr, twi);
    #pragma unroll
    for (int r = 0; r < 2; ++r) {
        const int base = (((wv << 1) | r) << 9) + lane;
        float ar[8], ai[8];
        #pragma unroll
        for (int j = 0; j < 8; ++j) {
            const int p = SW(base + (j << 6));
            ar[j] = re[p]; ai[j] = im[p];
        }
        if (INV) dit_apply<3>(ar, ai, twr, twi);
        else     dif_apply<3>(ar, ai, twr, twi);
        #pragma unroll
        for (int j = 0; j < 8; ++j) {
            const int p = SW(base + (j << 6));
            re[p] = ar[j]; im[p] = ai[j];
        }
    }
}

// M2: spans 32/16/8 within each 64-block. lane -> (b = lane>>3, r = lane&7),
// elements b*64 + r + 8j.
template<bool INV>
__device__ __forceinline__ void mid_M2(float* re, float* im, int lane, int wv) {
    float twr[7], twi[7];
    const float sgn = INV ? 1.0f : -1.0f;
    fill_pyr<2>(sgn * (TWO_PI / 64.0f) * (float)(lane & 7), CP4, sgn * SP4, twr, twi);
    const int sub = ((lane >> 3) << 6) + (lane & 7);
    #pragma unroll
    for (int r = 0; r < 2; ++r) {
        const int base = (((wv << 1) | r) << 9) + sub;
        float ar[8], ai[8];
        #pragma unroll
        for (int j = 0; j < 8; ++j) {
            const int p = SW(base + (j << 3));
            ar[j] = re[p]; ai[j] = im[p];
        }
        if (INV) dit_apply<3>(ar, ai, twr, twi);
        else     dif_apply<3>(ar, ai, twr, twi);
        #pragma unroll
        for (int j = 0; j < 8; ++j) {
            const int p = SW(base + (j << 3));
            re[p] = ar[j]; im[p] = ai[j];
        }
    }
}

__global__ __launch_bounds__(NT, 4) void conv_kernel(const float* __restrict__ u,
                                                     const float2* __restrict__ Kf,
                                                     float* __restrict__ out) {
    __shared__ float re[LL];
    __shared__ float im[LL];
    const int tid = threadIdx.x;
    const int h = blockIdx.x & (HH - 1);
    const int pr_ = blockIdx.x >> 8;        // batch pair 0..3
    const size_t off0 = ((size_t)(pr_ * 2) * HH + h) * LL;
    const size_t off1 = off0 + (size_t)HH * LL;
    const float* u0 = u + off0;
    const float* u1 = u + off1;

    float xr[16], xi[16];
    #pragma unroll
    for (int m = 0; m < 16; ++m) {
        xr[m] = u0[tid + (m << 9)];
        xi[m] = u1[tid + (m << 9)];
    }
    fwd_A(xr, xi, tid, re, im);       // z = u0 + i*u1
    __syncthreads();

    const int lane = tid & 63, wv = tid >> 6;
    const int c0 = (wv << 1);               // wave's chunks: c0, c0+1

    // kw prefetch for both rounds (dwordx4, per-lane contiguous), consumed in M3
    // a full M1+M2 later.
    float kwr[2][8], kwi[2][8];
    #pragma unroll
    for (int r = 0; r < 2; ++r) {
        const int eb = ((c0 | r) << 9) + (lane << 3);
        const float4* kp = (const float4*)(Kf + (size_t)h * LL + eb);
        #pragma unroll
        for (int jj = 0; jj < 4; ++jj) {
            const float4 v = kp[jj];
            kwr[r][2 * jj] = v.x;     kwi[r][2 * jj] = v.y;
            kwr[r][2 * jj + 1] = v.z; kwi[r][2 * jj + 1] = v.w;
        }
    }

    // ---- wave-private middle: no __syncthreads until pass A' ----
    mid_M1<false>(re, im, lane, wv);
    mid_M2<false>(re, im, lane, wv);

    // Merged M3: spans 4/2/1 fwd, *kw, inverse 1/2/4. Constant pyramids.
    {
        float twd_r[7], twd_i[7], twu_r[7], twu_i[7];
        fill_pyr_cs<2>(1.0f, 0.0f, CP4, -SP4, twd_r, twd_i);
        fill_pyr_cs<2>(1.0f, 0.0f, CP4, SP4, twu_r, twu_i);
        #pragma unroll
        for (int r = 0; r < 2; ++r) {
            const int eb = ((c0 | r) << 9) + (lane << 3);
            float yr[8], yi[8];
            #pragma unroll
            for (int j = 0; j < 8; ++j) {
                const int p = SW(eb + j);
                yr[j] = re[p]; yi[j] = im[p];
            }
            dif_apply<3>(yr, yi, twd_r, twd_i);
            #pragma unroll
            for (int j = 0; j < 8; ++j) {
                const float a = yr[j], b = yi[j];
                yr[j] = a * kwr[r][j] - b * kwi[r][j];
                yi[j] = a * kwi[r][j] + b * kwr[r][j];
            }
            dit_apply<3>(yr, yi, twu_r, twu_i);
            #pragma unroll
            for (int j = 0; j < 8; ++j) {
                const int p = SW(eb + j);
                re[p] = yr[j]; im[p] = yi[j];
            }
        }
    }

    mid_M2<true>(re, im, lane, wv);
    mid_M1<true>(re, im, lane, wv);
    __syncthreads();

    // Inv pass A' (spans 512..4096) + epilogue (skip/norm folded into kw).
    {
        float twr[15], twi[15];
        #pragma unroll
        for (int m = 0; m < 16; ++m) {
            const int p = SW(tid + (m << 9));
            xr[m] = re[p]; xi[m] = im[p];
        }
        fill_pyr<3>((TWO_PI / 8192.0f) * (float)tid, CP8, SP8, twr, twi);
        dit_apply<4>(xr, xi, twr, twi);
    }
    float* o0 = out + off0;
    float* o1 = out + off1;
    #pragma unroll
    for (int m = 0; m < 16; ++m) {
        const int n = tid + (m << 9);
        o0[n] = fast_tanh(xr[m]);
        o1[n] = fast_tanh(xi[m]);
    }
}

// ---------------- kfft, stage 1: elementwise DIF spans 4096 + 2048 ----------------
// For each h, m in [0,2048): A=K[m], B=K[m+2048], C=K[m+4096], D=K[m+6144]:
//   z[m]      = A+B+C+D                  (real)
//   z[m+2048] = (A+C-B-D) * W1^2
//   z[m+4096] = W1   * ((A-C) - i(B-D))
//   z[m+6144] = W1^3 * ((A-C) + i(B-D))     with W1 = exp(-2*pi*i*m/8192).
// Pure streaming: 8 MB read, 16 MB write. Natural element positions.
__global__ __launch_bounds__(256) void kfft1_kernel(const float* __restrict__ K,
                                                    float2* __restrict__ Kf) {
    const int b = blockIdx.x;
    const int h = b >> 3, seg = b & 7;
    const int m = (seg << 8) + threadIdx.x;           // [0, 2048)
    const float* Kr = K + (size_t)h * LL;
    const float A = Kr[m];
    const float B = Kr[m + 2048];
    const float C = Kr[m + 4096];
    const float E = Kr[m + 6144];
    float sn, cs;
    __sincosf(-(TWO_PI / 8192.0f) * (float)m, &sn, &cs);   // W1 = (cs, sn)
    const float c2 = cs * cs - sn * sn, s2 = 2.0f * cs * sn;        // W1^2
    const float c3 = cs * c2 - sn * s2, s3 = cs * s2 + sn * c2;     // W1^3
    const float p = A - C, q = B - E;
    const float sum = A + C + B + E;
    const float dif = A + C - B - E;
    float2* o = Kf + (size_t)h * LL;
    o[m]        = make_float2(sum, 0.0f);
    o[m + 2048] = make_float2(dif * c2, dif * s2);
    o[m + 4096] = make_float2(p * cs + q * sn, p * sn - q * cs);
    o[m + 6144] = make_float2(p * c3 - q * s3, p * s3 + q * c3);
}

// ---------------- kfft, stage 2: independent 2048-pt FFT per block ----------------
// Block (h, cq): in-place on Kf chunk [h*8192 + cq*2048, +2048). NT=256, 8
// elems/thread, 16 KB LDS, 1 barrier. Reg pass spans 1024/512/256; M1 spans
// 128/64/32 (t=tid&31, sub=tid>>5); M2 spans 16/8/4 (blk=tid>>2, r=tid&3; same
// wave as M1's writers: both wave blk>>4 -> no barrier); spans 2/1 via
// __shfl_xor(2)/(1) with W4 in {1,-i}; fold kw=(X+D[h])/N; store natural order.
__global__ __launch_bounds__(256) void kfft2_kernel(float2* __restrict__ Kf,
                                                    const float* __restrict__ D) {
    __shared__ float re[2048];
    __shared__ float im[2048];
    const int b = blockIdx.x;
    const int h = b >> 2, cq = b & 3;
    const int tid = threadIdx.x;
    float2* base = Kf + (size_t)h * LL + (cq << 11);

    float xr[8], xi[8];
    #pragma unroll
    for (int m = 0; m < 8; ++m) {
        const float2 v = base[tid + (m << 8)];
        xr[m] = v.x; xi[m] = v.y;
    }
    // Reg pass: spans 1024/512/256. Twiddles W_2048^{tid+256*mm}.
    {
        float twr[7], twi[7];
        fill_pyr<2>(-(TWO_PI / 2048.0f) * (float)tid, CP4, -SP4, twr, twi);
        dif_apply<3>(xr, xi, twr, twi);
    }
    #pragma unroll
    for (int m = 0; m < 8; ++m) {
        const int p = SW2(tid + (m << 8));
        re[p] = xr[m]; im[p] = xi[m];
    }
    __syncthreads();

    // M1: spans 128/64/32 on 256-subFFT sub=tid>>5, t=tid&31; elems sub*256+t+32j.
    {
        const int t_ = tid & 31, sub = tid >> 5;
        float twr[7], twi[7];
        fill_pyr<2>(-(TWO_PI / 256.0f) * (float)t_, CP4, -SP4, twr, twi);
        const int be = (sub << 8) + t_;
        float ar[8], ai[8];
        #pragma unroll
        for (int j = 0; j < 8; ++j) {
            const int p = SW2(be + (j << 5));
            ar[j] = re[p]; ai[j] = im[p];
        }
        dif_apply<3>(ar, ai, twr, twi);
        #pragma unroll
        for (int j = 0; j < 8; ++j) {
            const int p = SW2(be + (j << 5));
            re[p] = ar[j]; im[p] = ai[j];
        }
    }
    // M1 -> M2 handoff is same-wave (writer tids [(blk>>3)*32,+32), reader tids
    // [blk*4,+4), both wave blk>>4): no barrier.

    // M2: spans 16/8/4 on 32-subFFT blk=tid>>2, r=tid&3; elems blk*32+r+4j.
    {
        const int blk = tid >> 2, r = tid & 3;
        float twr[7], twi[7];
        fill_pyr<2>(-(TWO_PI / 32.0f) * (float)r, CP4, -SP4, twr, twi);
        const int eb = (blk << 5) + r;
        float yr[8], yi[8];
        #pragma unroll
        for (int j = 0; j < 8; ++j) {
            const int p = SW2(eb + (j << 2));
            yr[j] = re[p]; yi[j] = im[p];
        }
        dif_apply<3>(yr, yi, twr, twi);
        // span 2: pair (r, r+2); out[r<2] = a+b; out[r>=2] = (a-b)*W4^(r-2),
        // W4^0 = 1, W4^1 = -i.
        const float s2 = (r < 2) ? 1.0f : -1.0f;
        #pragma unroll
        for (int j = 0; j < 8; ++j) {
            const float vr = __shfl_xor(yr[j], 2);
            const float vi = __shfl_xor(yi[j], 2);
            const float tr = fmaf(yr[j], s2, vr);
            const float ti = fmaf(yi[j], s2, vi);
            yr[j] = (r == 3) ? ti : tr;
            yi[j] = (r == 3) ? -tr : ti;
        }
        // span 1: pair (even, odd), twiddle 1.
        const float s1 = (r & 1) ? -1.0f : 1.0f;
        #pragma unroll
        for (int j = 0; j < 8; ++j) {
            const float vr = __shfl_xor(yr[j], 1);
            const float vi = __shfl_xor(yi[j], 1);
            yr[j] = fmaf(yr[j], s1, vr);
            yi[j] = fmaf(yi[j], s1, vi);
        }
        // Fold kw = (X + D[h])/N and store (in-place, natural positions).
        const float dh = D[h];
        const float invN = 1.0f / (float)LL;
        #pragma unroll
        for (int j = 0; j < 8; ++j) {
            base[eb + (j << 2)] = make_float2((yr[j] + dh) * invN, yi[j] * invN);
        }
    }
}

extern "C" void kernel_launch(void* const* d_in, const int* in_sizes, int n_in,
                              void* d_out, int out_size, void* d_ws, size_t ws_size,
                              hipStream_t stream) {
    const float* u = (const float*)d_in[0];   // (8, 256, 8192)
    const float* K = (const float*)d_in[1];   // (256, 8192)
    const float* D = (const float*)d_in[2];   // (256,)
    float* out = (float*)d_out;               // (8, 256, 8192)
    float2* Kf = (float2*)d_ws;               // 256 * 8192 float2 = 16 MB

    kfft1_kernel<<<dim3(8 * HH), dim3(256), 0, stream>>>(K, Kf);
    kfft2_kernel<<<dim3(4 * HH), dim3(256), 0, stream>>>(Kf, D);
    conv_kernel<<<dim3(4 * HH), dim3(NT), 0, stream>>>(u, Kf, out);
}